// Round 5
// baseline (139.460 us; speedup 1.0000x reference)
//
#include <hip/hip_runtime.h>

// Problem constants (fixed by the reference setup)
#define B_   16
#define C_   64
#define H_   128
#define W_   128
#define HO   126
#define WO   126
#define NK   8     // number of conv kernels
#define ROWS 14    // output rows per band (126 = 9 * 14)
#define INR  16    // input rows staged = ROWS + 2
#define NB   9     // bands

// Persistent block per (c, b): loops over 9 bands with double-buffered LDS.
// Per band: issue next band's global load into registers (latency hides under
// compute), barrier, compute/store current band from s[cur], then SiLU+ds_write
// the prefetched data into s[cur^1]. One barrier per band.
// Compute mapping: wave w owns output kernel-plane k=w; lane l computes
// wo = l and wo = 64+l via a rolling 3-row tap window (6 LDS reads per row);
// weights in SGPRs.
__global__ __launch_bounds__(512) void conv_silu_kernel(
    const float* __restrict__ x, const float* __restrict__ Wt,
    float* __restrict__ out)
{
    __shared__ float s[2][INR][W_];   // 2 * 16 * 128 * 4 B = 16 KiB

    const int c   = blockIdx.x;       // 0..63
    const int b   = blockIdx.y;       // 0..15
    const int tid = threadIdx.x;      // 0..511
    const int row = tid >> 5;         // staging row (32 float4 per row)
    const int col = (tid & 31) << 2;  // staging col

    const float* xp = x + (size_t)(b * C_ + c) * H_ * W_;

    // ---- weights: wave w -> kernel k=w; scalar loads into SGPRs ----
    const int l  = tid & 63;
    const int ws = __builtin_amdgcn_readfirstlane((int)(threadIdx.x >> 6));
    float w9[9];
#pragma unroll
    for (int j = 0; j < 9; ++j) w9[j] = Wt[ws * 9 + j];

    // ---- prologue: stage band 0 (rows 0..15) into s[0] ----
    {
        const float4 v = ((const float4*)xp)[tid];
        float4 sv;
        sv.x = v.x * __builtin_amdgcn_rcpf(1.0f + __expf(-v.x));
        sv.y = v.y * __builtin_amdgcn_rcpf(1.0f + __expf(-v.y));
        sv.z = v.z * __builtin_amdgcn_rcpf(1.0f + __expf(-v.z));
        sv.w = v.w * __builtin_amdgcn_rcpf(1.0f + __expf(-v.w));
        *(float4*)&s[0][row][col] = sv;
    }

    float* opb = out + (size_t)((b * C_ + c) * NK + ws) * HO * WO;

    for (int band = 0; band < NB; ++band) {
        const int cur = band & 1;

        // issue next band's load early; vmcnt wait happens only at the
        // SiLU+ds_write below, after the compute phase.
        float4 vn;
        if (band < NB - 1)
            vn = ((const float4*)(xp + (size_t)(ROWS * (band + 1)) * W_))[tid];

        __syncthreads();   // s[cur] fully written; s[cur^1] no longer read

        // ---- compute band from s[cur] ----
        float* op = opb + (size_t)band * ROWS * WO;

        float tA[3][3], tB[3][3];
#pragma unroll
        for (int j = 0; j < 3; ++j) {
#pragma unroll
            for (int d = 0; d < 3; ++d) {
                tA[j][d] = s[cur][j][l + d];                // cols 0..65
                tB[j][d] = s[cur][j][(64 + l + d) & 127];   // masked lanes junk
            }
        }

#pragma unroll
        for (int r = 0; r < ROWS; ++r) {
            float accA = 0.f, accB = 0.f;
#pragma unroll
            for (int j = 0; j < 3; ++j) {
#pragma unroll
                for (int d = 0; d < 3; ++d) {
                    const float ww = w9[j * 3 + d];
                    accA += ww * tA[j][d];
                    accB += ww * tB[j][d];
                }
            }
            op[r * WO + l] = accA;                     // wo = 0..63
            if (l < 62) op[r * WO + 64 + l] = accB;    // wo = 64..125

            if (r < ROWS - 1) {
#pragma unroll
                for (int j = 0; j < 2; ++j) {
#pragma unroll
                    for (int d = 0; d < 3; ++d) {
                        tA[j][d] = tA[j + 1][d];
                        tB[j][d] = tB[j + 1][d];
                    }
                }
#pragma unroll
                for (int d = 0; d < 3; ++d) {
                    tA[2][d] = s[cur][r + 3][l + d];
                    tB[2][d] = s[cur][r + 3][(64 + l + d) & 127];
                }
            }
        }

        // ---- SiLU + stage prefetched band into the other buffer ----
        if (band < NB - 1) {
            float4 sv;
            sv.x = vn.x * __builtin_amdgcn_rcpf(1.0f + __expf(-vn.x));
            sv.y = vn.y * __builtin_amdgcn_rcpf(1.0f + __expf(-vn.y));
            sv.z = vn.z * __builtin_amdgcn_rcpf(1.0f + __expf(-vn.z));
            sv.w = vn.w * __builtin_amdgcn_rcpf(1.0f + __expf(-vn.w));
            *(float4*)&s[cur ^ 1][row][col] = sv;
        }
    }
}

extern "C" void kernel_launch(void* const* d_in, const int* in_sizes, int n_in,
                              void* d_out, int out_size, void* d_ws, size_t ws_size,
                              hipStream_t stream) {
    const float* x  = (const float*)d_in[0];   // [16,64,128,128] f32
    const float* Wt = (const float*)d_in[1];   // [8,9] f32
    float* out = (float*)d_out;                // [16,512,126,126] f32

    dim3 grid(C_, B_);   // persistent block per (channel, batch)
    conv_silu_kernel<<<grid, 512, 0, stream>>>(x, Wt, out);
}

// Round 6
// 129.950 us; speedup vs baseline: 1.0732x; 1.0732x over previous
//
#include <hip/hip_runtime.h>

// Problem constants (fixed by the reference setup)
#define B_   16
#define C_   64
#define H_   128
#define W_   128
#define HO   126
#define WO   126
#define NK   8     // number of conv kernels
#define ROWS 14    // output rows per band (126 = 9 * 14)
#define INR  16    // input rows staged = ROWS + 2

// Block = (band, channel, batch), 256 threads = 4 waves, 8 blocks/CU.
// Wave w owns output kernel-planes k=2w and 2w+1: the 3x3 tap window is shared
// across the k-pair, so 6 LDS reads per row yield 4 outputs. Each plane is
// written as a contiguous, monotonically ascending 7 KB stream.
// Lane l computes wo = l and wo = 64+l via a rolling 3-row tap window;
// weights live in SGPRs (readfirstlane'd wave index -> scalar loads).
__global__ __launch_bounds__(256, 8) void conv_silu_kernel(
    const float* __restrict__ x, const float* __restrict__ Wt,
    float* __restrict__ out)
{
    __shared__ float s[INR][W_];   // 16 * 128 * 4 B = 8 KiB

    const int band = blockIdx.x;   // 0..8
    const int c    = blockIdx.y;   // 0..63
    const int b    = blockIdx.z;   // 0..15
    const int tid  = threadIdx.x;  // 0..255
    const int ho0  = band * ROWS;

    // ---- stage input band (16 rows x 128 cols) with SiLU applied ----
    // 2048 floats = 512 float4; 256 threads x 2. Always in-bounds:
    // ho0 max = 112, +15 = 127 = H-1.
    {
        const float4* xv =
            (const float4*)(x + ((size_t)(b * C_ + c) * H_ + ho0) * W_);
#pragma unroll
        for (int i = 0; i < 2; ++i) {
            const int f   = tid + i * 256;       // float4 index 0..511
            const float4 v = xv[f];
            const int row = f >> 5;              // 32 float4 per row
            const int col = (f & 31) << 2;
            float4 sv;
            sv.x = v.x * __builtin_amdgcn_rcpf(1.0f + __expf(-v.x));
            sv.y = v.y * __builtin_amdgcn_rcpf(1.0f + __expf(-v.y));
            sv.z = v.z * __builtin_amdgcn_rcpf(1.0f + __expf(-v.z));
            sv.w = v.w * __builtin_amdgcn_rcpf(1.0f + __expf(-v.w));
            *(float4*)&s[row][col] = sv;         // ds_write_b128
        }
    }
    __syncthreads();

    // ---- compute: wave w handles kernels k = 2w, 2w+1 ----
    const int l  = tid & 63;
    const int ws = __builtin_amdgcn_readfirstlane((int)(threadIdx.x >> 6)); // SGPR

    float w0[9], w1[9];   // scalar loads (uniform address) -> SGPRs
#pragma unroll
    for (int j = 0; j < 9; ++j) {
        w0[j] = Wt[(2 * ws    ) * 9 + j];
        w1[j] = Wt[(2 * ws + 1) * 9 + j];
    }

    float* opA = out + ((size_t)((b * C_ + c) * NK + 2 * ws) * HO + ho0) * WO;
    float* opB = opA + (size_t)HO * WO;

    // Rolling tap window: t*[j][d] = silu(x)[input row r+j][wo + d]
    float tA[3][3], tB[3][3];
#pragma unroll
    for (int j = 0; j < 3; ++j) {
#pragma unroll
        for (int d = 0; d < 3; ++d) {
            tA[j][d] = s[j][l + d];                // cols 0..65, in-bounds
            tB[j][d] = s[j][(64 + l + d) & 127];   // masked lanes read junk, ok
        }
    }

#pragma unroll
    for (int r = 0; r < ROWS; ++r) {
        float a0 = 0.f, a1 = 0.f, b0 = 0.f, b1 = 0.f;
#pragma unroll
        for (int j = 0; j < 3; ++j) {
#pragma unroll
            for (int d = 0; d < 3; ++d) {
                const float q0 = w0[j * 3 + d];
                const float q1 = w1[j * 3 + d];
                a0 += q0 * tA[j][d];
                a1 += q1 * tA[j][d];
                b0 += q0 * tB[j][d];
                b1 += q1 * tB[j][d];
            }
        }
        opA[r * WO + l] = a0;                       // k=2w,  wo = 0..63
        opB[r * WO + l] = a1;                       // k=2w+1
        if (l < 62) {
            opA[r * WO + 64 + l] = b0;              // wo = 64..125
            opB[r * WO + 64 + l] = b1;
        }

        if (r < ROWS - 1) {
            // rotate window and pull in input row r+3 (max 15 = INR-1)
#pragma unroll
            for (int j = 0; j < 2; ++j) {
#pragma unroll
                for (int d = 0; d < 3; ++d) {
                    tA[j][d] = tA[j + 1][d];
                    tB[j][d] = tB[j + 1][d];
                }
            }
#pragma unroll
            for (int d = 0; d < 3; ++d) {
                tA[2][d] = s[r + 3][l + d];
                tB[2][d] = s[r + 3][(64 + l + d) & 127];
            }
        }
    }
}

extern "C" void kernel_launch(void* const* d_in, const int* in_sizes, int n_in,
                              void* d_out, int out_size, void* d_ws, size_t ws_size,
                              hipStream_t stream) {
    const float* x  = (const float*)d_in[0];   // [16,64,128,128] f32
    const float* Wt = (const float*)d_in[1];   // [8,9] f32
    float* out = (float*)d_out;                // [16,512,126,126] f32

    dim3 grid(9, C_, B_);   // (bands, channels, batch)
    conv_silu_kernel<<<grid, 256, 0, stream>>>(x, Wt, out);
}